// Round 8
// baseline (235.760 us; speedup 1.0000x reference)
//
#include <hip/hip_runtime.h>
#include <hip/hip_bf16.h>

// Shapes (fixed): B=4, H=56, W=56, C=256, NH=8, HD=32, KS=7, PAD=3
// tokens M = 4*56*56 = 12544. Padded k/v planes: [4][64][64][256] bf16,
// interior token (y,x) at plane row y+3, col x+3; border zeroed by prep.
//
// R16: dot2 QK + bf16 qf + packed-f32 PV: 139.8 -> 133.0 (best config).
// R18: fusion dead end; ground truth: whole-pipeline VALU ~20us, MFMA ~2.6us,
//      HBM ~17us.
// R21 MEASUREMENT: attn x2 -> 53.0us row in counters => attn single ~26.5us,
//      VALUBusy 57%, Occ 38%, FETCH 11.8MB, 0 conflicts, HBM 5.9%.
//      => prep+qkv+proj+gaps ~= 100us of the 133 -- UNEXPLAINED by work
//      models (~20us). One of them is 4-5x worse than modeled.
// R22 (this round) MEASUREMENT #2: attn reverted to 6272. prep x8 (40960
//      blocks, bid%5120) and qkv x8 (grid 48x98, n0=(bx%6)*128); all
//      duplicate work is same-value/idempotent -> output bit-identical.
//      Solve: dur-133 = 7(P+Q); the larger of 8P/8Q tops the counter rows
//      giving its exact dur; derive both. proj = 133 - 26.5 - P - Q - gaps.

using frag_ab = __attribute__((ext_vector_type(8))) short;  // 8 bf16 (4 VGPRs)
using f32x4   = __attribute__((ext_vector_type(4))) float;  // 4 fp32 acc
using f32x2   = __attribute__((ext_vector_type(2))) float;  // packed f32 pair

typedef const __attribute__((address_space(1))) unsigned int* gas_u32;
typedef __attribute__((address_space(3))) unsigned int*       las_u32;

__device__ __forceinline__ void gl_lds16(const void* g, void* l) {
    // async global->LDS DMA, 16 B/lane; LDS dst = wave-uniform base + lane*16
    __builtin_amdgcn_global_load_lds((gas_u32)g, (las_u32)l, 16, 0, 0);
}

__device__ __forceinline__ float bflo(unsigned int u) { return __uint_as_float(u << 16); }
__device__ __forceinline__ float bfhi(unsigned int u) { return __uint_as_float(u & 0xffff0000u); }

__device__ __forceinline__ f32x2 unpk2(unsigned int u) {
    f32x2 r; r.x = bflo(u); r.y = bfhi(u); return r;
}

#if defined(__has_builtin)
#if __has_builtin(__builtin_amdgcn_fdot2_f32_bf16)
#define HAVE_FDOT2_BF16 1
#endif
#endif

#ifdef HAVE_FDOT2_BF16
typedef __bf16 bf16x2 __attribute__((ext_vector_type(2)));
__device__ __forceinline__ float dot2bf(unsigned int a, unsigned int b, float c) {
    union { unsigned int u; bf16x2 h; } ua, ub;
    ua.u = a; ub.u = b;
    return __builtin_amdgcn_fdot2_f32_bf16(ua.h, ub.h, c, false);
}
#endif

// ================= fused prep (R22: x8 via bid % 5120) =================
// virtual blocks [0,3136):    x fp32 -> xb bf16 (float4/thread)
// virtual blocks [3136,3904): w_qkv [256][768] -> wqkvT [768][256] bf16
// virtual blocks [3904,4160): w_proj [256][256] -> wprojT [256][256] bf16
// virtual blocks [4160,5120): zero the 960 border cols of each padded plane
__global__ __launch_bounds__(256) void prep_k(
    const float* __restrict__ x,      __hip_bfloat16* __restrict__ xb,
    const float* __restrict__ w_qkv,  __hip_bfloat16* __restrict__ wqkvT,
    const float* __restrict__ w_proj, __hip_bfloat16* __restrict__ wprojT,
    __hip_bfloat16* __restrict__ kp,  __hip_bfloat16* __restrict__ vp)
{
    const int bid = blockIdx.x % 5120;   // R22: x8 duplicate, idempotent
    const int tid = threadIdx.x;
    if (bid < 3136) {
        const int i = bid * 256 + tid;            // over M*256/4 = 802816
        const float4 v = ((const float4*)x)[i];
        union { ushort4 u; __hip_bfloat16 h[4]; } o;
        o.h[0] = __float2bfloat16(v.x); o.h[1] = __float2bfloat16(v.y);
        o.h[2] = __float2bfloat16(v.z); o.h[3] = __float2bfloat16(v.w);
        ((ushort4*)xb)[i] = o.u;
    } else if (bid < 3904) {
        const int idx = (bid - 3136) * 256 + tid; // over 768*256
        const int k = idx & 255, n = idx >> 8;
        wqkvT[idx] = __float2bfloat16(w_qkv[k * 768 + n]);
    } else if (bid < 4160) {
        const int idx = (bid - 3904) * 256 + tid; // over 256*256
        const int k = idx & 255, n = idx >> 8;
        wprojT[idx] = __float2bfloat16(w_proj[k * 256 + n]);
    } else {
        const int u    = (bid - 4160) * 256 + tid;   // over 8*30720
        const int ip   = u / 30720;                  // img*2 + plane
        const int rem  = u - ip * 30720;
        const int cloc = rem >> 5;                   // 0..959 border cells
        const int q16  = rem & 31;                   // 16B chunk of 256 ch
        const int img  = ip >> 1;
        __hip_bfloat16* base = (ip & 1) ? vp : kp;
        int prow, pcol;
        if (cloc < 512) {                            // full pad rows 0-2,59-63
            const int r8 = cloc >> 6;
            prow = (r8 < 3) ? r8 : r8 + 56;
            pcol = cloc & 63;
        } else {                                     // side pads of rows 3..58
            const int c2 = cloc - 512;
            prow = 3 + (c2 >> 3);
            const int cc = c2 & 7;
            pcol = (cc < 3) ? cc : cc + 56;
        }
        *(uint4*)(base + (((size_t)(img * 64 + prow)) * 64 + pcol) * 256 + q16 * 8) =
            make_uint4(0u, 0u, 0u, 0u);
    }
}

// ================= qkv GEMM, 128x128, single-buffer (R16-measured-best) =====
// R22: launched 48x98; n0 = (blockIdx.x % 6)*128 -> x8 idempotent duplicate.
__global__ __launch_bounds__(256) void gemm_qkv_k(
    const __hip_bfloat16* __restrict__ A,       // xb (M,256) bf16
    const __hip_bfloat16* __restrict__ BT,      // wqkvT (768,256) bf16
    const float* __restrict__ bias,
    __hip_bfloat16* __restrict__ qf,
    __hip_bfloat16* __restrict__ kp,
    __hip_bfloat16* __restrict__ vp,
    float qscale)
{
    constexpr int K = 256;
    __shared__ frag_ab As[8][64];   // 8 KB
    __shared__ frag_ab Bs[8][64];   // 8 KB

    const int tid  = threadIdx.x;
    const int lane = tid & 63;
    const int w    = tid >> 6;
    const int wm   = w >> 1, wn = w & 1;
    const int m0 = blockIdx.y * 128;
    const int n0 = (blockIdx.x % 6) * 128;      // R22: x8 duplicate

    const int lrow = lane & 15;
    const int lk   = (lane >> 4) * 8;
    const __hip_bfloat16* gA0 = A  + (size_t)(m0 + (2*w+0)*16 + lrow) * K + lk;
    const __hip_bfloat16* gA1 = A  + (size_t)(m0 + (2*w+1)*16 + lrow) * K + lk;
    const __hip_bfloat16* gB0 = BT + (size_t)(n0 + (2*w+0)*16 + lrow) * K + lk;
    const __hip_bfloat16* gB1 = BT + (size_t)(n0 + (2*w+1)*16 + lrow) * K + lk;

    f32x4 acc[4][4] = {};

    for (int k0 = 0; k0 < K; k0 += 32) {
        gl_lds16(gA0 + k0, &As[2*w+0][0]);
        gl_lds16(gA1 + k0, &As[2*w+1][0]);
        gl_lds16(gB0 + k0, &Bs[2*w+0][0]);
        gl_lds16(gB1 + k0, &Bs[2*w+1][0]);
        __syncthreads();
        frag_ab af[4], bf[4];
        #pragma unroll
        for (int i = 0; i < 4; ++i) { af[i] = As[wm*4+i][lane]; bf[i] = Bs[wn*4+i][lane]; }
        #pragma unroll
        for (int i = 0; i < 4; ++i)
            #pragma unroll
            for (int j = 0; j < 4; ++j)
                acc[i][j] = __builtin_amdgcn_mfma_f32_16x16x32_bf16(af[i], bf[j], acc[i][j], 0, 0, 0);
        __syncthreads();
    }

    const int rbase = (lane >> 4) * 4;
    const int cbase = lane & 15;
    #pragma unroll
    for (int fi = 0; fi < 4; ++fi) {
        const int rm = m0 + wm * 64 + fi * 16 + rbase;
        #pragma unroll
        for (int fj = 0; fj < 4; ++fj) {
            const int cn = n0 + wn * 64 + fj * 16 + cbase;
            const float bv = bias[cn];
            #pragma unroll
            for (int r = 0; r < 4; ++r) {
                const int mm  = rm + r;
                const float val = acc[fi][fj][r] + bv;
                const int sel = cn >> 8;                   // 0=q,1=k,2=v
                if (sel == 0) {
                    qf[(size_t)mm * 256 + cn] = __float2bfloat16(val * qscale);
                } else {
                    const int c  = cn & 255;
                    const int bb = mm / 3136;
                    const int r2 = mm % 3136;
                    const int yy = r2 / 56;
                    const int xx = r2 % 56;
                    __hip_bfloat16* dst = (sel == 1) ? kp : vp;
                    dst[(((size_t)(bb * 64 + yy + 3)) * 64 + (xx + 3)) * 256 + c] =
                        __float2bfloat16(val);
                }
            }
        }
    }
}

// ===== proj GEMM, 64x64 tile, single-buffer (R2/R14-validated) ==============
__global__ __launch_bounds__(256) void gemm_proj_k(
    const __hip_bfloat16* __restrict__ A,
    const __hip_bfloat16* __restrict__ BT,
    const float* __restrict__ bias,
    float* __restrict__ C)
{
    constexpr int K = 256;
    __shared__ frag_ab As[4][64];   // 4 KB
    __shared__ frag_ab Bs[4][64];   // 4 KB

    const int tid  = threadIdx.x;
    const int lane = tid & 63;
    const int w    = tid >> 6;
    const int wm   = w >> 1, wn = w & 1;
    const int m0 = blockIdx.y * 64;
    const int n0 = blockIdx.x * 64;

    const int lrow = lane & 15;
    const int lk   = (lane >> 4) * 8;
    const __hip_bfloat16* gA = A  + (size_t)(m0 + w * 16 + lrow) * K + lk;
    const __hip_bfloat16* gB = BT + (size_t)(n0 + w * 16 + lrow) * K + lk;

    f32x4 acc[2][2] = {};

    for (int k0 = 0; k0 < K; k0 += 32) {
        gl_lds16(gA + k0, &As[w][0]);
        gl_lds16(gB + k0, &Bs[w][0]);
        __syncthreads();
        const frag_ab a0 = As[2 * wm + 0][lane];
        const frag_ab a1 = As[2 * wm + 1][lane];
        const frag_ab b0 = Bs[2 * wn + 0][lane];
        const frag_ab b1 = Bs[2 * wn + 1][lane];
        acc[0][0] = __builtin_amdgcn_mfma_f32_16x16x32_bf16(a0, b0, acc[0][0], 0, 0, 0);
        acc[0][1] = __builtin_amdgcn_mfma_f32_16x16x32_bf16(a0, b1, acc[0][1], 0, 0, 0);
        acc[1][0] = __builtin_amdgcn_mfma_f32_16x16x32_bf16(a1, b0, acc[1][0], 0, 0, 0);
        acc[1][1] = __builtin_amdgcn_mfma_f32_16x16x32_bf16(a1, b1, acc[1][1], 0, 0, 0);
        __syncthreads();
    }

    const int rbase = (lane >> 4) * 4;
    const int cbase = lane & 15;
    #pragma unroll
    for (int fi = 0; fi < 2; ++fi) {
        const int rm = m0 + wm * 32 + fi * 16 + rbase;
        #pragma unroll
        for (int fj = 0; fj < 2; ++fj) {
            const int cn = n0 + wn * 32 + fj * 16 + cbase;
            const float bv = bias[cn];
            #pragma unroll
            for (int r = 0; r < 4; ++r)
                C[(size_t)(rm + r) * 256 + cn] = acc[fi][fj][r] + bv;
        }
    }
}

// ================= neighborhood attention (R17-verified body, grid 6272) ====
__global__ __launch_bounds__(64) void na2d_attn_k(
    const __hip_bfloat16* __restrict__ qf,
    const __hip_bfloat16* __restrict__ kp,
    const __hip_bfloat16* __restrict__ vp,
    const float* __restrict__ rpb,
    __hip_bfloat16* __restrict__ out)
{
    const int lane = threadIdx.x;       // 0..63
    const int q8   = lane & 3;          // quarter-head: 8-ch slice
    const int h    = (lane >> 2) & 7;   // head
    const int tl   = (lane >> 5) & 1;   // token within 2-token segment

    const int bid = blockIdx.x;         // 0..6271
    const int seg = (bid & 7) * 784 + (bid >> 3);   // XCD-contiguous remap
    const int row = seg / 28;           // b*56 + y
    const int x0  = (seg % 28) * 2;     // 0..54
    const int b   = row / 56;
    const int y   = row % 56;
    const int t   = row * 56 + x0 + tl;
    const int prow0 = b * 64 + y;       // padded plane row for ky=0

    __shared__ __hip_bfloat16 kbuf[8 * 256];    // 4 KB, linear [8 cols][256 ch]
    __shared__ float srpb[8 * 49];

    for (int i = lane; i < 8 * 49; i += 64) srpb[i] = rpb[i];
    __syncthreads();                    // single-wave barrier: cheap

    // q: 8 bf16 channels, kept PACKED (4 uints)
    unsigned int qpk[4];
    {
        const uint4 qa = *(const uint4*)(qf + (size_t)t * 256 + h * 32 + q8 * 8);
        qpk[0] = qa.x; qpk[1] = qa.y; qpk[2] = qa.z; qpk[3] = qa.w;
    }
#ifndef HAVE_FDOT2_BF16
    f32x2 q2[4];
    #pragma unroll
    for (int i = 0; i < 4; ++i) q2[i] = unpk2(qpk[i]);
#endif

    const int wroff = lane * 16;                    // linear LDS write
    const int rdoff = tl * 512 + h * 64 + q8 * 16;  // + kx*512 per window col

#define GLOAD4(plane, ky, d0, d1, d2, d3)                                       \
    do {                                                                        \
        const char* rb_ = (const char*)((plane) +                               \
            ((size_t)(prow0 + (ky)) * 64 + x0) * 256 + lane * 8);               \
        d0 = *(const uint4*)(rb_);                                              \
        d1 = *(const uint4*)(rb_ + 1024);                                       \
        d2 = *(const uint4*)(rb_ + 2048);                                       \
        d3 = *(const uint4*)(rb_ + 3072);                                       \
    } while (0)

#define LWRITE4(buf, s0, s1, s2, s3)                                            \
    do {                                                                        \
        char* wb_ = (char*)(buf) + wroff;                                       \
        *(uint4*)(wb_)        = s0;                                             \
        *(uint4*)(wb_ + 1024) = s1;                                             \
        *(uint4*)(wb_ + 2048) = s2;                                             \
        *(uint4*)(wb_ + 3072) = s3;                                             \
    } while (0)

    const float* rp = &srpb[h * 49];
    float m = -1e30f, l = 0.f;
    f32x2 o2[4] = {};

    uint4 k0, k1, k2, k3;
    GLOAD4(kp, 0, k0, k1, k2, k3);

    #pragma unroll 1
    for (int ky = 0; ky < 7; ++ky) {
        LWRITE4(kbuf, k0, k1, k2, k3);          // waits vmcnt for k row only
        // per-lane direct v loads: this lane's 8 ch for its 7 cols (R15)
        const __hip_bfloat16* vrow = vp +
            ((size_t)(prow0 + ky) * 64 + x0 + tl) * 256 + h * 32 + q8 * 8;
        uint4 va[7];
        #pragma unroll
        for (int kx = 0; kx < 7; ++kx)
            va[kx] = *(const uint4*)(vrow + kx * 256);
        // k-prefetch AFTER v loads: PV's vmcnt waits never drain it
        if (ky < 6) GLOAD4(kp, ky + 1, k0, k1, k2, k3);
        // ---- 7 row logits from kbuf ----
        float lg[7];
        #pragma unroll
        for (int kx = 0; kx < 7; ++kx) {
            const uint4 w0 = *(const uint4*)((const char*)kbuf + rdoff + kx * 512);
#ifdef HAVE_FDOT2_BF16
            float s = 0.f;
            s = dot2bf(qpk[0], w0.x, s);
            s = dot2bf(qpk[1], w0.y, s);
            s = dot2bf(qpk[2], w0.z, s);
            s = dot2bf(qpk[3], w0.w, s);
#else
            f32x2 s2 = {0.f, 0.f};
            s2 += q2[0] * unpk2(w0.x);
            s2 += q2[1] * unpk2(w0.y);
            s2 += q2[2] * unpk2(w0.z);
            s2 += q2[3] * unpk2(w0.w);
            const float s = s2.x + s2.y;
#endif
            lg[kx] = s;
        }
        // ---- merge quarter-head partials (lanes ^1, ^2) + rpb ----
        #pragma unroll
        for (int kx = 0; kx < 7; ++kx) {
            lg[kx] += __shfl_xor(lg[kx], 1, 64);
            lg[kx] += __shfl_xor(lg[kx], 2, 64);
            lg[kx] += rp[ky * 7 + kx];
        }
        // ---- online softmax update ----
        float rmax = lg[0];
        #pragma unroll
        for (int kx = 1; kx < 7; ++kx) rmax = fmaxf(rmax, lg[kx]);
        const float mnew  = fmaxf(m, rmax);
        const float alpha = __expf(m - mnew);   // ky=0: exp(-inf)=0
        m = mnew;
        l *= alpha;
        const f32x2 alpha2 = {alpha, alpha};
        #pragma unroll
        for (int i = 0; i < 4; ++i) o2[i] *= alpha2;
        // ---- PV from direct-loaded registers, packed-f32 accumulate ----
        #pragma unroll
        for (int kx = 0; kx < 7; ++kx) {
            const float pr = __expf(lg[kx] - mnew);
            l += pr;
            const f32x2 pr2 = {pr, pr};
            const uint4 w0 = va[kx];
            o2[0] += pr2 * unpk2(w0.x);
            o2[1] += pr2 * unpk2(w0.y);
            o2[2] += pr2 * unpk2(w0.z);
            o2[3] += pr2 * unpk2(w0.w);
        }
    }
#undef GLOAD4
#undef LWRITE4

    // ---- store bf16 (feeds proj GEMM) ----
    const float inv = 1.f / l;
    union { uint4 u; __hip_bfloat16 hh[8]; } ob;
    #pragma unroll
    for (int i = 0; i < 4; ++i) {
        ob.hh[2 * i + 0] = __float2bfloat16(o2[i].x * inv);
        ob.hh[2 * i + 1] = __float2bfloat16(o2[i].y * inv);
    }
    *(uint4*)(out + (size_t)t * 256 + h * 32 + q8 * 8) = ob.u;
}

// ===================== host =====================
extern "C" void kernel_launch(void* const* d_in, const int* in_sizes, int n_in,
                              void* d_out, int out_size, void* d_ws, size_t ws_size,
                              hipStream_t stream)
{
    const float* x      = (const float*)d_in[0];   // (4,56,56,256)
    const float* w_qkv  = (const float*)d_in[1];   // (256,768)
    const float* b_qkv  = (const float*)d_in[2];   // (768,)
    const float* rpb    = (const float*)d_in[3];   // (8,49)
    const float* w_proj = (const float*)d_in[4];   // (256,256)
    const float* b_proj = (const float*)d_in[5];   // (256,)
    float* out = (float*)d_out;                    // (4,56,56,256) fp32

    const int M = 12544;

    char* wsp = (char*)d_ws;
    __hip_bfloat16* qf    = (__hip_bfloat16*)wsp; wsp += (size_t)M * 256 * 2;          // 6.4 MB
    __hip_bfloat16* kp    = (__hip_bfloat16*)wsp; wsp += (size_t)4 * 64 * 64 * 256 * 2; // 8.39 MB
    __hip_bfloat16* vp    = (__hip_bfloat16*)wsp; wsp += (size_t)4 * 64 * 64 * 256 * 2; // 8.39 MB
    __hip_bfloat16* xb    = (__hip_bfloat16*)wsp; wsp += (size_t)M * 256 * 2;
    __hip_bfloat16* attnb = (__hip_bfloat16*)wsp; wsp += (size_t)M * 256 * 2;
    __hip_bfloat16* wqkvT = (__hip_bfloat16*)wsp; wsp += (size_t)768 * 256 * 2;
    __hip_bfloat16* wprojT= (__hip_bfloat16*)wsp; wsp += (size_t)256 * 256 * 2;

    const float scale = 0.17677669529663689f;  // 32^-0.5

    // prep x8 (R22 measurement; idempotent duplicates)
    prep_k<<<40960, 256, 0, stream>>>(x, xb, w_qkv, wqkvT, w_proj, wprojT, kp, vp);

    // qkv x8 (R22 measurement; idempotent duplicates)
    gemm_qkv_k<<<dim3(48, 98), 256, 0, stream>>>(xb, wqkvT, b_qkv, qf, kp, vp, scale);

    // attention: normal 6272 blocks
    na2d_attn_k<<<6272, 64, 0, stream>>>(qf, kp, vp, rpb, attnb);

    // out = attnb @ wprojT^T + b_proj
    gemm_proj_k<<<dim3(4, 196), 256, 0, stream>>>(attnb, wprojT, b_proj, out);
}

// Round 9
// 131.030 us; speedup vs baseline: 1.7993x; 1.7993x over previous
//
#include <hip/hip_runtime.h>
#include <hip/hip_bf16.h>

// Shapes (fixed): B=4, H=56, W=56, C=256, NH=8, HD=32, KS=7, PAD=3
// tokens M = 4*56*56 = 12544. Padded k/v planes: [4][64][64][256] bf16,
// interior token (y,x) at plane row y+3, col x+3; border zeroed by prep.
//
// Measured budget (R21/R22 inflation probes): attn ~34us (VALUBusy 57%,
// Occ 38%, 0 conflicts, HBM 6%), qkv ~20-25us (MfmaUtil 13%, VALUBusy 40%,
// Occ 30% at x8), ~43us harness re-poison fill inside the timed region
// (untouchable), prep/proj/gaps = remainder (~30us, unmeasured split).
// R16: dot2 QK + bf16 qf + packed-f32 PV: 139.8 -> 133.0 (best verified).
// R18: grid.sync fusion dead end (270us). R19: in-loop cvt +4.6. R20:
// 2-phase GEMM pipeline +2.4 (MFMA too short to cover load latency).
// R23 (this round): qkv retile 128x128 -> 64x128. 588 -> 1176 blocks
// (2.3 -> 4.6/CU; same lever as R14's proj win); BN=128 makes the q/k/v
// select BLOCK-UNIFORM (kills per-element branch); epilogue halves per
// thread and row div-chains hoisted out of the fj loop. prep/attn/proj
// unchanged verified forms; all R22 duplication multipliers reverted.

using frag_ab = __attribute__((ext_vector_type(8))) short;  // 8 bf16 (4 VGPRs)
using f32x4   = __attribute__((ext_vector_type(4))) float;  // 4 fp32 acc
using f32x2   = __attribute__((ext_vector_type(2))) float;  // packed f32 pair

typedef const __attribute__((address_space(1))) unsigned int* gas_u32;
typedef __attribute__((address_space(3))) unsigned int*       las_u32;

__device__ __forceinline__ void gl_lds16(const void* g, void* l) {
    // async global->LDS DMA, 16 B/lane; LDS dst = wave-uniform base + lane*16
    __builtin_amdgcn_global_load_lds((gas_u32)g, (las_u32)l, 16, 0, 0);
}

__device__ __forceinline__ float bflo(unsigned int u) { return __uint_as_float(u << 16); }
__device__ __forceinline__ float bfhi(unsigned int u) { return __uint_as_float(u & 0xffff0000u); }

__device__ __forceinline__ f32x2 unpk2(unsigned int u) {
    f32x2 r; r.x = bflo(u); r.y = bfhi(u); return r;
}

#if defined(__has_builtin)
#if __has_builtin(__builtin_amdgcn_fdot2_f32_bf16)
#define HAVE_FDOT2_BF16 1
#endif
#endif

#ifdef HAVE_FDOT2_BF16
typedef __bf16 bf16x2 __attribute__((ext_vector_type(2)));
__device__ __forceinline__ float dot2bf(unsigned int a, unsigned int b, float c) {
    union { unsigned int u; bf16x2 h; } ua, ub;
    ua.u = a; ub.u = b;
    return __builtin_amdgcn_fdot2_f32_bf16(ua.h, ub.h, c, false);
}
#endif

// ================= fused prep =================
// blocks [0,3136):    x fp32 -> xb bf16 (float4/thread)
// blocks [3136,3904): w_qkv [256][768] -> wqkvT [768][256] bf16
// blocks [3904,4160): w_proj [256][256] -> wprojT [256][256] bf16
// blocks [4160,5120): zero the 960 border cols of each padded plane
__global__ __launch_bounds__(256) void prep_k(
    const float* __restrict__ x,      __hip_bfloat16* __restrict__ xb,
    const float* __restrict__ w_qkv,  __hip_bfloat16* __restrict__ wqkvT,
    const float* __restrict__ w_proj, __hip_bfloat16* __restrict__ wprojT,
    __hip_bfloat16* __restrict__ kp,  __hip_bfloat16* __restrict__ vp)
{
    const int bid = blockIdx.x;
    const int tid = threadIdx.x;
    if (bid < 3136) {
        const int i = bid * 256 + tid;            // over M*256/4 = 802816
        const float4 v = ((const float4*)x)[i];
        union { ushort4 u; __hip_bfloat16 h[4]; } o;
        o.h[0] = __float2bfloat16(v.x); o.h[1] = __float2bfloat16(v.y);
        o.h[2] = __float2bfloat16(v.z); o.h[3] = __float2bfloat16(v.w);
        ((ushort4*)xb)[i] = o.u;
    } else if (bid < 3904) {
        const int idx = (bid - 3136) * 256 + tid; // over 768*256
        const int k = idx & 255, n = idx >> 8;
        wqkvT[idx] = __float2bfloat16(w_qkv[k * 768 + n]);
    } else if (bid < 4160) {
        const int idx = (bid - 3904) * 256 + tid; // over 256*256
        const int k = idx & 255, n = idx >> 8;
        wprojT[idx] = __float2bfloat16(w_proj[k * 256 + n]);
    } else {
        const int u    = (bid - 4160) * 256 + tid;   // over 8*30720
        const int ip   = u / 30720;                  // img*2 + plane
        const int rem  = u - ip * 30720;
        const int cloc = rem >> 5;                   // 0..959 border cells
        const int q16  = rem & 31;                   // 16B chunk of 256 ch
        const int img  = ip >> 1;
        __hip_bfloat16* base = (ip & 1) ? vp : kp;
        int prow, pcol;
        if (cloc < 512) {                            // full pad rows 0-2,59-63
            const int r8 = cloc >> 6;
            prow = (r8 < 3) ? r8 : r8 + 56;
            pcol = cloc & 63;
        } else {                                     // side pads of rows 3..58
            const int c2 = cloc - 512;
            prow = 3 + (c2 >> 3);
            const int cc = c2 & 7;
            pcol = (cc < 3) ? cc : cc + 56;
        }
        *(uint4*)(base + (((size_t)(img * 64 + prow)) * 64 + pcol) * 256 + q16 * 8) =
            make_uint4(0u, 0u, 0u, 0u);
    }
}

// ================= qkv GEMM, 64x128 tile (R23) =================
// Grid (6,196) = 1176 blocks (~4.6/CU). 256 thr = 4 waves; wave (wm,wn)
// owns 32 rows x 64 cols = 2x4 16x16x32 fragments. Staging in fragment
// order: wave w DMAs A row-block w and B row-blocks 2w,2w+1. Each block's
// 128-col range is entirely q, k, or v -> sel is BLOCK-UNIFORM.
__global__ __launch_bounds__(256) void gemm_qkv_k(
    const __hip_bfloat16* __restrict__ A,       // xb (M,256) bf16
    const __hip_bfloat16* __restrict__ BT,      // wqkvT (768,256) bf16
    const float* __restrict__ bias,
    __hip_bfloat16* __restrict__ qf,
    __hip_bfloat16* __restrict__ kp,
    __hip_bfloat16* __restrict__ vp,
    float qscale)
{
    constexpr int K = 256;
    __shared__ frag_ab As[4][64];   // 4 KB (64 rows x 32 k)
    __shared__ frag_ab Bs[8][64];   // 8 KB (128 cols x 32 k)

    const int tid  = threadIdx.x;
    const int lane = tid & 63;
    const int w    = tid >> 6;
    const int wm   = w >> 1, wn = w & 1;
    const int m0 = blockIdx.y * 64;
    const int n0 = blockIdx.x * 128;

    const int lrow = lane & 15;
    const int lk   = (lane >> 4) * 8;
    const __hip_bfloat16* gA  = A  + (size_t)(m0 + w * 16 + lrow) * K + lk;
    const __hip_bfloat16* gB0 = BT + (size_t)(n0 + (2*w+0)*16 + lrow) * K + lk;
    const __hip_bfloat16* gB1 = BT + (size_t)(n0 + (2*w+1)*16 + lrow) * K + lk;

    f32x4 acc[2][4] = {};

    for (int k0 = 0; k0 < K; k0 += 32) {
        gl_lds16(gA  + k0, &As[w][0]);
        gl_lds16(gB0 + k0, &Bs[2*w+0][0]);
        gl_lds16(gB1 + k0, &Bs[2*w+1][0]);
        __syncthreads();
        frag_ab af[2], bf[4];
        #pragma unroll
        for (int i = 0; i < 2; ++i) af[i] = As[2*wm + i][lane];
        #pragma unroll
        for (int j = 0; j < 4; ++j) bf[j] = Bs[wn*4 + j][lane];
        #pragma unroll
        for (int i = 0; i < 2; ++i)
            #pragma unroll
            for (int j = 0; j < 4; ++j)
                acc[i][j] = __builtin_amdgcn_mfma_f32_16x16x32_bf16(af[i], bf[j], acc[i][j], 0, 0, 0);
        __syncthreads();
    }

    // ---- epilogue: sel is block-uniform (n0 in {0,128}=q, {256,384}=k,
    // {512,640}=v); row div-chains hoisted out of the fj loop ----
    const int sel  = n0 >> 8;
    const int rbase = (lane >> 4) * 4;
    const int cbase = lane & 15;
    __hip_bfloat16* dstp = (sel == 1) ? kp : vp;    // unused when sel==0

    #pragma unroll
    for (int fi = 0; fi < 2; ++fi) {
        #pragma unroll
        for (int r = 0; r < 4; ++r) {
            const int mm = m0 + wm * 32 + fi * 16 + rbase + r;
            size_t rowbase;
            if (sel == 0) {
                rowbase = (size_t)mm * 256;
            } else {
                const int bb = mm / 3136;
                const int r2 = mm % 3136;
                const int yy = r2 / 56;
                const int xx = r2 % 56;
                rowbase = (((size_t)(bb * 64 + yy + 3)) * 64 + (xx + 3)) * 256;
            }
            #pragma unroll
            for (int fj = 0; fj < 4; ++fj) {
                const int cn = n0 + wn * 64 + fj * 16 + cbase;
                const float val = acc[fi][fj][r] + bias[cn];
                if (sel == 0) {
                    qf[rowbase + cn] = __float2bfloat16(val * qscale);
                } else {
                    dstp[rowbase + (cn & 255)] = __float2bfloat16(val);
                }
            }
        }
    }
}

// ===== proj GEMM, 64x64 tile, single-buffer (R2/R14-validated) ==============
__global__ __launch_bounds__(256) void gemm_proj_k(
    const __hip_bfloat16* __restrict__ A,
    const __hip_bfloat16* __restrict__ BT,
    const float* __restrict__ bias,
    float* __restrict__ C)
{
    constexpr int K = 256;
    __shared__ frag_ab As[4][64];   // 4 KB
    __shared__ frag_ab Bs[4][64];   // 4 KB

    const int tid  = threadIdx.x;
    const int lane = tid & 63;
    const int w    = tid >> 6;
    const int wm   = w >> 1, wn = w & 1;
    const int m0 = blockIdx.y * 64;
    const int n0 = blockIdx.x * 64;

    const int lrow = lane & 15;
    const int lk   = (lane >> 4) * 8;
    const __hip_bfloat16* gA = A  + (size_t)(m0 + w * 16 + lrow) * K + lk;
    const __hip_bfloat16* gB = BT + (size_t)(n0 + w * 16 + lrow) * K + lk;

    f32x4 acc[2][2] = {};

    for (int k0 = 0; k0 < K; k0 += 32) {
        gl_lds16(gA + k0, &As[w][0]);
        gl_lds16(gB + k0, &Bs[w][0]);
        __syncthreads();
        const frag_ab a0 = As[2 * wm + 0][lane];
        const frag_ab a1 = As[2 * wm + 1][lane];
        const frag_ab b0 = Bs[2 * wn + 0][lane];
        const frag_ab b1 = Bs[2 * wn + 1][lane];
        acc[0][0] = __builtin_amdgcn_mfma_f32_16x16x32_bf16(a0, b0, acc[0][0], 0, 0, 0);
        acc[0][1] = __builtin_amdgcn_mfma_f32_16x16x32_bf16(a0, b1, acc[0][1], 0, 0, 0);
        acc[1][0] = __builtin_amdgcn_mfma_f32_16x16x32_bf16(a1, b0, acc[1][0], 0, 0, 0);
        acc[1][1] = __builtin_amdgcn_mfma_f32_16x16x32_bf16(a1, b1, acc[1][1], 0, 0, 0);
        __syncthreads();
    }

    const int rbase = (lane >> 4) * 4;
    const int cbase = lane & 15;
    #pragma unroll
    for (int fi = 0; fi < 2; ++fi) {
        const int rm = m0 + wm * 32 + fi * 16 + rbase;
        #pragma unroll
        for (int fj = 0; fj < 2; ++fj) {
            const int cn = n0 + wn * 32 + fj * 16 + cbase;
            const float bv = bias[cn];
            #pragma unroll
            for (int r = 0; r < 4; ++r)
                C[(size_t)(rm + r) * 256 + cn] = acc[fi][fj][r] + bv;
        }
    }
}

// ================= neighborhood attention (R17-verified body, grid 6272) ====
__global__ __launch_bounds__(64) void na2d_attn_k(
    const __hip_bfloat16* __restrict__ qf,
    const __hip_bfloat16* __restrict__ kp,
    const __hip_bfloat16* __restrict__ vp,
    const float* __restrict__ rpb,
    __hip_bfloat16* __restrict__ out)
{
    const int lane = threadIdx.x;       // 0..63
    const int q8   = lane & 3;          // quarter-head: 8-ch slice
    const int h    = (lane >> 2) & 7;   // head
    const int tl   = (lane >> 5) & 1;   // token within 2-token segment

    const int bid = blockIdx.x;         // 0..6271
    const int seg = (bid & 7) * 784 + (bid >> 3);   // XCD-contiguous remap
    const int row = seg / 28;           // b*56 + y
    const int x0  = (seg % 28) * 2;     // 0..54
    const int b   = row / 56;
    const int y   = row % 56;
    const int t   = row * 56 + x0 + tl;
    const int prow0 = b * 64 + y;       // padded plane row for ky=0

    __shared__ __hip_bfloat16 kbuf[8 * 256];    // 4 KB, linear [8 cols][256 ch]
    __shared__ float srpb[8 * 49];

    for (int i = lane; i < 8 * 49; i += 64) srpb[i] = rpb[i];
    __syncthreads();                    // single-wave barrier: cheap

    // q: 8 bf16 channels, kept PACKED (4 uints)
    unsigned int qpk[4];
    {
        const uint4 qa = *(const uint4*)(qf + (size_t)t * 256 + h * 32 + q8 * 8);
        qpk[0] = qa.x; qpk[1] = qa.y; qpk[2] = qa.z; qpk[3] = qa.w;
    }
#ifndef HAVE_FDOT2_BF16
    f32x2 q2[4];
    #pragma unroll
    for (int i = 0; i < 4; ++i) q2[i] = unpk2(qpk[i]);
#endif

    const int wroff = lane * 16;                    // linear LDS write
    const int rdoff = tl * 512 + h * 64 + q8 * 16;  // + kx*512 per window col

#define GLOAD4(plane, ky, d0, d1, d2, d3)                                       \
    do {                                                                        \
        const char* rb_ = (const char*)((plane) +                               \
            ((size_t)(prow0 + (ky)) * 64 + x0) * 256 + lane * 8);               \
        d0 = *(const uint4*)(rb_);                                              \
        d1 = *(const uint4*)(rb_ + 1024);                                       \
        d2 = *(const uint4*)(rb_ + 2048);                                       \
        d3 = *(const uint4*)(rb_ + 3072);                                       \
    } while (0)

#define LWRITE4(buf, s0, s1, s2, s3)                                            \
    do {                                                                        \
        char* wb_ = (char*)(buf) + wroff;                                       \
        *(uint4*)(wb_)        = s0;                                             \
        *(uint4*)(wb_ + 1024) = s1;                                             \
        *(uint4*)(wb_ + 2048) = s2;                                             \
        *(uint4*)(wb_ + 3072) = s3;                                             \
    } while (0)

    const float* rp = &srpb[h * 49];
    float m = -1e30f, l = 0.f;
    f32x2 o2[4] = {};

    uint4 k0, k1, k2, k3;
    GLOAD4(kp, 0, k0, k1, k2, k3);

    #pragma unroll 1
    for (int ky = 0; ky < 7; ++ky) {
        LWRITE4(kbuf, k0, k1, k2, k3);          // waits vmcnt for k row only
        // per-lane direct v loads: this lane's 8 ch for its 7 cols (R15)
        const __hip_bfloat16* vrow = vp +
            ((size_t)(prow0 + ky) * 64 + x0 + tl) * 256 + h * 32 + q8 * 8;
        uint4 va[7];
        #pragma unroll
        for (int kx = 0; kx < 7; ++kx)
            va[kx] = *(const uint4*)(vrow + kx * 256);
        // k-prefetch AFTER v loads: PV's vmcnt waits never drain it
        if (ky < 6) GLOAD4(kp, ky + 1, k0, k1, k2, k3);
        // ---- 7 row logits from kbuf ----
        float lg[7];
        #pragma unroll
        for (int kx = 0; kx < 7; ++kx) {
            const uint4 w0 = *(const uint4*)((const char*)kbuf + rdoff + kx * 512);
#ifdef HAVE_FDOT2_BF16
            float s = 0.f;
            s = dot2bf(qpk[0], w0.x, s);
            s = dot2bf(qpk[1], w0.y, s);
            s = dot2bf(qpk[2], w0.z, s);
            s = dot2bf(qpk[3], w0.w, s);
#else
            f32x2 s2 = {0.f, 0.f};
            s2 += q2[0] * unpk2(w0.x);
            s2 += q2[1] * unpk2(w0.y);
            s2 += q2[2] * unpk2(w0.z);
            s2 += q2[3] * unpk2(w0.w);
            const float s = s2.x + s2.y;
#endif
            lg[kx] = s;
        }
        // ---- merge quarter-head partials (lanes ^1, ^2) + rpb ----
        #pragma unroll
        for (int kx = 0; kx < 7; ++kx) {
            lg[kx] += __shfl_xor(lg[kx], 1, 64);
            lg[kx] += __shfl_xor(lg[kx], 2, 64);
            lg[kx] += rp[ky * 7 + kx];
        }
        // ---- online softmax update ----
        float rmax = lg[0];
        #pragma unroll
        for (int kx = 1; kx < 7; ++kx) rmax = fmaxf(rmax, lg[kx]);
        const float mnew  = fmaxf(m, rmax);
        const float alpha = __expf(m - mnew);   // ky=0: exp(-inf)=0
        m = mnew;
        l *= alpha;
        const f32x2 alpha2 = {alpha, alpha};
        #pragma unroll
        for (int i = 0; i < 4; ++i) o2[i] *= alpha2;
        // ---- PV from direct-loaded registers, packed-f32 accumulate ----
        #pragma unroll
        for (int kx = 0; kx < 7; ++kx) {
            const float pr = __expf(lg[kx] - mnew);
            l += pr;
            const f32x2 pr2 = {pr, pr};
            const uint4 w0 = va[kx];
            o2[0] += pr2 * unpk2(w0.x);
            o2[1] += pr2 * unpk2(w0.y);
            o2[2] += pr2 * unpk2(w0.z);
            o2[3] += pr2 * unpk2(w0.w);
        }
    }
#undef GLOAD4
#undef LWRITE4

    // ---- store bf16 (feeds proj GEMM) ----
    const float inv = 1.f / l;
    union { uint4 u; __hip_bfloat16 hh[8]; } ob;
    #pragma unroll
    for (int i = 0; i < 4; ++i) {
        ob.hh[2 * i + 0] = __float2bfloat16(o2[i].x * inv);
        ob.hh[2 * i + 1] = __float2bfloat16(o2[i].y * inv);
    }
    *(uint4*)(out + (size_t)t * 256 + h * 32 + q8 * 8) = ob.u;
}

// ===================== host =====================
extern "C" void kernel_launch(void* const* d_in, const int* in_sizes, int n_in,
                              void* d_out, int out_size, void* d_ws, size_t ws_size,
                              hipStream_t stream)
{
    const float* x      = (const float*)d_in[0];   // (4,56,56,256)
    const float* w_qkv  = (const float*)d_in[1];   // (256,768)
    const float* b_qkv  = (const float*)d_in[2];   // (768,)
    const float* rpb    = (const float*)d_in[3];   // (8,49)
    const float* w_proj = (const float*)d_in[4];   // (256,256)
    const float* b_proj = (const float*)d_in[5];   // (256,)
    float* out = (float*)d_out;                    // (4,56,56,256) fp32

    const int M = 12544;

    char* wsp = (char*)d_ws;
    __hip_bfloat16* qf    = (__hip_bfloat16*)wsp; wsp += (size_t)M * 256 * 2;          // 6.4 MB
    __hip_bfloat16* kp    = (__hip_bfloat16*)wsp; wsp += (size_t)4 * 64 * 64 * 256 * 2; // 8.39 MB
    __hip_bfloat16* vp    = (__hip_bfloat16*)wsp; wsp += (size_t)4 * 64 * 64 * 256 * 2; // 8.39 MB
    __hip_bfloat16* xb    = (__hip_bfloat16*)wsp; wsp += (size_t)M * 256 * 2;
    __hip_bfloat16* attnb = (__hip_bfloat16*)wsp; wsp += (size_t)M * 256 * 2;
    __hip_bfloat16* wqkvT = (__hip_bfloat16*)wsp; wsp += (size_t)768 * 256 * 2;
    __hip_bfloat16* wprojT= (__hip_bfloat16*)wsp; wsp += (size_t)256 * 256 * 2;

    const float scale = 0.17677669529663689f;  // 32^-0.5

    // fused prep: x->bf16, both weight transposes, pad-border zero of kp/vp
    prep_k<<<5120, 256, 0, stream>>>(x, xb, w_qkv, wqkvT, w_proj, wprojT, kp, vp);

    // qkv = xb @ wqkvT^T + b_qkv (64x128 tile, 1176 blocks, R23)
    gemm_qkv_k<<<dim3(6, 196), 256, 0, stream>>>(xb, wqkvT, b_qkv, qf, kp, vp, scale);

    // attention: 6272 blocks x 64 threads (R17-verified body)
    na2d_attn_k<<<6272, 64, 0, stream>>>(qf, kp, vp, rpb, attnb);

    // out = attnb @ wprojT^T + b_proj
    gemm_proj_k<<<dim3(4, 196), 256, 0, stream>>>(attnb, wprojT, b_proj, out);
}